// Round 8
// baseline (512.966 us; speedup 1.0000x reference)
//
#include <hip/hip_runtime.h>

typedef short v8s __attribute__((ext_vector_type(8)));
typedef unsigned short v8us __attribute__((ext_vector_type(8)));
typedef float v4f __attribute__((ext_vector_type(4)));
typedef float v2f __attribute__((ext_vector_type(2)));
typedef unsigned int uint;
typedef unsigned short ushort_t;

#define N_NODES 100000
#define N_EDGES 1600000
#define NBUCK 782           // ceil(100000/128); bucket = dst>>7
#define TILE 4096
#define NTILE 391           // ceil(1600000/4096)
#define NB_CONV 12500       // 3.2M 4-elem feature groups / 256
#define AXLD 136            // LDS ax row stride (shorts): 272 B = 17 x 16 B, keeps b128 align

__device__ __forceinline__ float b2f(unsigned short u) {
    return __uint_as_float(((uint)u) << 16);
}
__device__ __forceinline__ unsigned short f2b(float f) {
    uint u = __float_as_uint(f);
    uint r = u + 0x7FFFu + ((u >> 16) & 1u);   // RNE
    return (unsigned short)(r >> 16);
}
// accumulate 2 bf16 (packed in one dword) into a float2 accumulator (v_pk_add_f32 path)
__device__ __forceinline__ void acc2_bf16(v2f& acc, uint d) {
    v2f t;
    t.x = __uint_as_float(d << 16);
    t.y = __uint_as_float(d & 0xFFFF0000u);
    acc += t;
}

// ---------------- dtype sniffer ----------------
__global__ void k_sniff(const uint* __restrict__ w, int* __restrict__ flag) {
    __shared__ int cnt;
    if (threadIdx.x == 0) cnt = 0;
    __syncthreads();
    int c = 0;
    for (int i = threadIdx.x; i < 4096; i += 256) {
        uint lo = w[i] & 0xFFFFu;
        uint ex = (lo >> 7) & 0xFFu;
        if ((ex >= 100u && ex <= 140u) || lo == 0u) c++;
    }
    atomicAdd(&cnt, c);
    __syncthreads();
    if (threadIdx.x == 0) *flag = (cnt >= 3000) ? 1 : 0;  // 1 = bf16, 0 = f32
}

// ---------------- weight conversion + transpose + bcnt zero ----------------
struct WConvArgs {
    const void* srcW[6];
    ushort_t* dstW[6];
};
__global__ __launch_bounds__(256) void k_conv_weights(WConvArgs a, const int* __restrict__ flag,
                                                      int* __restrict__ bcnt) {
    int b = blockIdx.x, tid = threadIdx.x;
    if (b == 304) {
        for (int i = tid; i < NBUCK; i += 256) bcnt[i] = 0;
        return;
    }
    int f = *flag;
    int j, lb, H;
    if (b < 256)      { j = b >> 6; lb = b & 63; H = 128; }
    else if (b < 276) { j = 4; lb = b - 256; H = 40; }
    else if (b < 280) {
        int idx = (b - 276) * 256 + tid;
        a.dstW[4][(40 + idx / 128) * 128 + (idx & 127)] = 0; return;
    }
    else if (b < 300) { j = 5; lb = b - 280; H = 40; }
    else {
        int idx = (b - 300) * 256 + tid;
        a.dstW[5][(40 + idx / 128) * 128 + (idx & 127)] = 0; return;
    }
    int idx = lb * 256 + tid;
    if (idx >= 128 * H) return;
    int k = idx / H, n = idx % H;
    ushort_t v;
    if (f) v = ((const ushort_t*)a.srcW[j])[idx];
    else   v = f2b(((const float*)a.srcW[j])[idx]);
    a.dstW[j][n * 128 + k] = v;
}

// ---------------- feature conversion (x4) fused with bucket histogram ----------------
__global__ __launch_bounds__(256) void k_convfeat_bhist(const void* __restrict__ in,
                                                        ushort_t* __restrict__ out,
                                                        const int* __restrict__ flag,
                                                        const int* __restrict__ dst,
                                                        int* __restrict__ bcnt) {
    __shared__ int h[NBUCK];
    int b = blockIdx.x, tid = threadIdx.x;
    if (b < NB_CONV) {
        int i = b * 256 + tid;
        if (*flag) {
            ((uint2*)out)[i] = ((const uint2*)in)[i];
        } else {
            float4 v = ((const float4*)in)[i];
            ushort4 o;
            o.x = f2b(v.x); o.y = f2b(v.y); o.z = f2b(v.z); o.w = f2b(v.w);
            ((ushort4*)out)[i] = o;
        }
        return;
    }
    int t = b - NB_CONV;
    for (int i = tid; i < NBUCK; i += 256) h[i] = 0;
    __syncthreads();
    int t0 = t * TILE;
    int t1 = t0 + TILE; if (t1 > N_EDGES) t1 = N_EDGES;
    for (int i = t0 + tid; i < t1; i += 256) atomicAdd(&h[dst[i] >> 7], 1);
    __syncthreads();
    for (int i = tid; i < NBUCK; i += 256)
        if (h[i]) atomicAdd(&bcnt[i], h[i]);
}

// ---------------- bucket scan ----------------
__global__ __launch_bounds__(1024) void k_bscan(const int* __restrict__ bcnt,
                                                int* __restrict__ boff,
                                                int* __restrict__ bcur) {
    __shared__ int sd[1024];
    int tid = threadIdx.x;
    int v = (tid < NBUCK) ? bcnt[tid] : 0;
    sd[tid] = v; __syncthreads();
    int val = v;
    for (int off = 1; off < 1024; off <<= 1) {
        int t = (tid >= off) ? sd[tid - off] : 0;
        __syncthreads();
        val += t; sd[tid] = val;
        __syncthreads();
    }
    if (tid < NBUCK) {
        int excl = val - v;
        boff[tid] = excl;
        bcur[tid] = excl;
    }
}

// ---------------- tile-local binning -> packed (dstLocal7 | src17) ----------------
__global__ __launch_bounds__(256) void k_bscatter(const int* __restrict__ src,
                                                  const int* __restrict__ dst,
                                                  int* __restrict__ bcur,
                                                  uint* __restrict__ packed) {
    __shared__ int h[NBUCK];
    __shared__ int base[NBUCK];
    int tid = threadIdx.x;
    for (int i = tid; i < NBUCK; i += 256) h[i] = 0;
    __syncthreads();
    int t0 = blockIdx.x * TILE;
    int t1 = t0 + TILE; if (t1 > N_EDGES) t1 = N_EDGES;
    for (int i = t0 + tid; i < t1; i += 256) atomicAdd(&h[dst[i] >> 7], 1);
    __syncthreads();
    for (int i = tid; i < NBUCK; i += 256) {
        int c = h[i];
        base[i] = c ? atomicAdd(&bcur[i], c) : 0;
        h[i] = 0;
    }
    __syncthreads();
    for (int i = t0 + tid; i < t1; i += 256) {
        int d = dst[i];
        int b = d >> 7;
        int r = atomicAdd(&h[b], 1);
        packed[base[b] + r] = ((uint)(d & 127) << 17) | (uint)src[i];
    }
}

// ---------------- one block per bucket: counting sort -> es, rs, inv_deg ----------------
__global__ __launch_bounds__(256) void k_binsort(const uint* __restrict__ packed,
                                                 const int* __restrict__ bcnt,
                                                 const int* __restrict__ boff,
                                                 int* __restrict__ rs,
                                                 float* __restrict__ inv_deg,
                                                 int* __restrict__ es) {
    __shared__ int hist[128], start[128], cur[128];
    int tid = threadIdx.x;
    int b = blockIdx.x;
    int nb = bcnt[b], off = boff[b];
    if (tid < 128) hist[tid] = 0;
    __syncthreads();
    for (int i = tid; i < nb; i += 256) atomicAdd(&hist[packed[off + i] >> 17], 1);
    __syncthreads();
    if (tid < 128) start[tid] = hist[tid];
    __syncthreads();
    for (int o = 1; o < 128; o <<= 1) {
        int v = (tid < 128 && tid >= o) ? start[tid - o] : 0;
        __syncthreads();
        if (tid < 128) start[tid] += v;
        __syncthreads();
    }
    if (tid < 128) {
        int excl = start[tid] - hist[tid];
        int node = b * 128 + tid;
        if (node < N_NODES) {
            rs[node] = off + excl;
            int d = hist[tid];
            inv_deg[node] = 1.0f / (float)(d > 1 ? d : 1);
        }
        cur[tid] = excl;
    }
    if (b == NBUCK - 1 && tid == 0) rs[N_NODES] = N_EDGES;
    __syncthreads();
    for (int i = tid; i < nb; i += 256) {
        uint p = packed[off + i];
        int k = p >> 17;
        int pos = atomicAdd(&cur[k], 1);
        es[off + pos] = (int)(p & 0x1FFFFu);
    }
}

// ---------------- Fused agg + dual-A GEMM (layers 1-2) ----------------
// Block = 1 dst-bucket (128 nodes), 512 threads (8 waves).
// Phase A: 32 lane-groups of 16; group owns one node, gathers & accumulates its edges
//          (no shuffles/atomics), writes bf16 ax row to LDS. 4 rounds cover 128 nodes.
// Phase B: dual GEMM out = relu(x@Ws + ax@Wn + bias); ax from LDS, x/W from global.
//          N in 2 halves of 64 to bound VGPRs.
template <bool RELU>
__global__ __launch_bounds__(512) void k_fused(
    const int* __restrict__ rs,
    const int* __restrict__ es,
    const float* __restrict__ inv_deg,
    const ushort_t* __restrict__ xg,     // gather table == self rows (read-only)
    const ushort_t* __restrict__ Wts,
    const ushort_t* __restrict__ Wtn,
    const float* __restrict__ bias,
    ushort_t* __restrict__ out,
    int n) {
    __shared__ ushort_t axs[128 * AXLD];   // 34.8 KB
    int tid = threadIdx.x;
    int b = blockIdx.x;

    // ---- Phase A ----
    {
        int gid = tid >> 4;          // 0..31 lane-group
        int lc = tid & 15;           // col group of 8 within row
        for (int r = 0; r < 4; ++r) {
            int nl = r * 32 + gid;
            int node = b * 128 + nl;
            v2f acc2[4];
            for (int i = 0; i < 4; ++i) acc2[i] = (v2f){0.f, 0.f};
            float inv = 0.f;
            if (node < n) {
                int s0 = rs[node], s1 = rs[node + 1];
                int e = s0;
                for (; e + 3 < s1; e += 4) {
                    int sA = es[e], sB = es[e + 1], sC = es[e + 2], sD = es[e + 3];
                    uint4 dA = *(const uint4*)(xg + (size_t)sA * 128 + lc * 8);
                    uint4 dB = *(const uint4*)(xg + (size_t)sB * 128 + lc * 8);
                    uint4 dC = *(const uint4*)(xg + (size_t)sC * 128 + lc * 8);
                    uint4 dD = *(const uint4*)(xg + (size_t)sD * 128 + lc * 8);
                    acc2_bf16(acc2[0], dA.x); acc2_bf16(acc2[1], dA.y); acc2_bf16(acc2[2], dA.z); acc2_bf16(acc2[3], dA.w);
                    acc2_bf16(acc2[0], dB.x); acc2_bf16(acc2[1], dB.y); acc2_bf16(acc2[2], dB.z); acc2_bf16(acc2[3], dB.w);
                    acc2_bf16(acc2[0], dC.x); acc2_bf16(acc2[1], dC.y); acc2_bf16(acc2[2], dC.z); acc2_bf16(acc2[3], dC.w);
                    acc2_bf16(acc2[0], dD.x); acc2_bf16(acc2[1], dD.y); acc2_bf16(acc2[2], dD.z); acc2_bf16(acc2[3], dD.w);
                }
                for (; e < s1; ++e) {
                    int sA = es[e];
                    uint4 dA = *(const uint4*)(xg + (size_t)sA * 128 + lc * 8);
                    acc2_bf16(acc2[0], dA.x); acc2_bf16(acc2[1], dA.y); acc2_bf16(acc2[2], dA.z); acc2_bf16(acc2[3], dA.w);
                }
                inv = inv_deg[node];
            }
            v8us ov;
            ov[0] = f2b(inv * acc2[0].x); ov[1] = f2b(inv * acc2[0].y);
            ov[2] = f2b(inv * acc2[1].x); ov[3] = f2b(inv * acc2[1].y);
            ov[4] = f2b(inv * acc2[2].x); ov[5] = f2b(inv * acc2[2].y);
            ov[6] = f2b(inv * acc2[3].x); ov[7] = f2b(inv * acc2[3].y);
            *(v8us*)(&axs[nl * AXLD + lc * 8]) = ov;
        }
    }
    __syncthreads();

    // ---- Phase B ----
    {
        int wave = tid >> 6, lane = tid & 63;
        int quad = lane >> 4, l16 = lane & 15;
        int rowA = b * 128 + wave * 16 + l16;
        int rowAc = (rowA < n) ? rowA : (n - 1);

        v8s a1[4], a2[4];
        for (int kk = 0; kk < 4; ++kk) {
            a1[kk] = *(const v8s*)(xg + (size_t)rowAc * 128 + kk * 32 + quad * 8);
            a2[kk] = *(const v8s*)(&axs[(wave * 16 + l16) * AXLD + kk * 32 + quad * 8]);
        }

        for (int half = 0; half < 2; ++half) {
            v4f accS[4], accN[4];
            for (int t = 0; t < 4; ++t) {
                accS[t] = (v4f){0.f, 0.f, 0.f, 0.f};
                accN[t] = (v4f){0.f, 0.f, 0.f, 0.f};
            }
            for (int t = 0; t < 4; ++t) {
                for (int kk = 0; kk < 4; ++kk) {
                    size_t bo = (size_t)((half * 4 + t) * 16 + l16) * 128 + kk * 32 + quad * 8;
                    const v8s bs = *(const v8s*)(Wts + bo);
                    const v8s bn = *(const v8s*)(Wtn + bo);
                    accS[t] = __builtin_amdgcn_mfma_f32_16x16x32_bf16(a1[kk], bs, accS[t], 0, 0, 0);
                    accN[t] = __builtin_amdgcn_mfma_f32_16x16x32_bf16(a2[kk], bn, accN[t], 0, 0, 0);
                }
            }
            for (int t = 0; t < 4; ++t) {
                int col = (half * 4 + t) * 16 + l16;
                float bv = bias[col];
                for (int rr = 0; rr < 4; ++rr) {
                    int row = b * 128 + wave * 16 + quad * 4 + rr;
                    if (row < n) {
                        float v = accS[t][rr] + accN[t][rr] + bv;
                        if (RELU) v = fmaxf(v, 0.f);
                        out[(size_t)row * 128 + col] = f2b(v);
                    }
                }
            }
        }
    }
}

// ---------------- Layer-3 split GEMM: y3 = x@Ws3+b3 (f32), h3 = x@Wn3 (bf16) ----------------
__global__ __launch_bounds__(256) void k_gemm_split_g(
    const ushort_t* __restrict__ x,
    const ushort_t* __restrict__ Wts,
    const ushort_t* __restrict__ Wtn,
    const float* __restrict__ bias,
    float* __restrict__ y3,
    ushort_t* __restrict__ h3,
    int n) {
    constexpr int H = 40;
    int tid = threadIdx.x;
    int wave = tid >> 6, lane = tid & 63;
    int quad = lane >> 4, l16 = lane & 15;
    int rowBase = blockIdx.x * 128 + wave * 32;

    v4f accS[2][3], accN[2][3];
    for (int rt = 0; rt < 2; ++rt)
        for (int t = 0; t < 3; ++t) {
            accS[rt][t] = (v4f){0.f, 0.f, 0.f, 0.f};
            accN[rt][t] = (v4f){0.f, 0.f, 0.f, 0.f};
        }

    for (int kk = 0; kk < 4; ++kk) {
        v8s a1[2];
        for (int rt = 0; rt < 2; ++rt) {
            int row = rowBase + rt * 16 + l16;
            if (row >= n) row = n - 1;
            a1[rt] = *(const v8s*)(x + (size_t)row * 128 + kk * 32 + quad * 8);
        }
        for (int t = 0; t < 3; ++t) {
            size_t bo = (size_t)(t * 16 + l16) * 128 + kk * 32 + quad * 8;
            const v8s bs = *(const v8s*)(Wts + bo);
            const v8s bn = *(const v8s*)(Wtn + bo);
            for (int rt = 0; rt < 2; ++rt) {
                accS[rt][t] = __builtin_amdgcn_mfma_f32_16x16x32_bf16(a1[rt], bs, accS[rt][t], 0, 0, 0);
                accN[rt][t] = __builtin_amdgcn_mfma_f32_16x16x32_bf16(a1[rt], bn, accN[rt][t], 0, 0, 0);
            }
        }
    }

    for (int rt = 0; rt < 2; ++rt)
        for (int t = 0; t < 3; ++t) {
            int col = t * 16 + l16;
            if (col < H) {
                float bv = bias[col];
                for (int r = 0; r < 4; ++r) {
                    int row = rowBase + rt * 16 + quad * 4 + r;
                    if (row < n) {
                        size_t o = (size_t)row * H + col;
                        y3[o] = accS[rt][t][r] + bv;
                        h3[o] = f2b(accN[rt][t][r]);
                    }
                }
            }
        }
}

// ---------------- Layer-3 aggregation (H=40): 8 slots x 8 cols (5 active), unroll x2 ----
__global__ __launch_bounds__(256) void k_agg3(
    const int* __restrict__ rs,
    const int* __restrict__ es,
    const float* __restrict__ inv_deg,
    const ushort_t* __restrict__ h3,
    const float* __restrict__ y3,
    void* out,
    const int* __restrict__ flag,
    int n) {
    int tid = threadIdx.x;
    int wave = tid >> 6, lane = tid & 63;
    int node = blockIdx.x * 4 + wave;
    if (node >= n) return;
    int sub = lane >> 3;        // 8 edge slots
    int cg = lane & 7;          // col group of 8 (0..4 active)
    bool act = (cg < 5);
    int outBf16 = *flag;

    int s0 = rs[node], s1 = rs[node + 1];
    v2f acc2[4];
    for (int i = 0; i < 4; ++i) acc2[i] = (v2f){0.f, 0.f};

    if (act) {
        int e = s0 + sub;
        for (; e + 8 < s1; e += 16) {
            int sA = es[e], sB = es[e + 8];
            uint4 dA = *(const uint4*)(h3 + (size_t)sA * 40 + cg * 8);
            uint4 dB = *(const uint4*)(h3 + (size_t)sB * 40 + cg * 8);
            acc2_bf16(acc2[0], dA.x); acc2_bf16(acc2[1], dA.y); acc2_bf16(acc2[2], dA.z); acc2_bf16(acc2[3], dA.w);
            acc2_bf16(acc2[0], dB.x); acc2_bf16(acc2[1], dB.y); acc2_bf16(acc2[2], dB.z); acc2_bf16(acc2[3], dB.w);
        }
        if (e < s1) {
            int sA = es[e];
            uint4 dA = *(const uint4*)(h3 + (size_t)sA * 40 + cg * 8);
            acc2_bf16(acc2[0], dA.x); acc2_bf16(acc2[1], dA.y); acc2_bf16(acc2[2], dA.z); acc2_bf16(acc2[3], dA.w);
        }
    }
    float acc[8];
    for (int i = 0; i < 4; ++i) { acc[2 * i] = acc2[i].x; acc[2 * i + 1] = acc2[i].y; }
    for (int off = 8; off < 64; off <<= 1)
        for (int i = 0; i < 8; ++i) acc[i] += __shfl_xor(acc[i], off);

    if (sub == 0 && act) {
        float inv = inv_deg[node];
        const float4* yp = (const float4*)(y3 + (size_t)node * 40 + cg * 8);
        float4 y0 = yp[0], y1 = yp[1];
        float o[8];
        o[0] = y0.x + inv * acc[0]; o[1] = y0.y + inv * acc[1];
        o[2] = y0.z + inv * acc[2]; o[3] = y0.w + inv * acc[3];
        o[4] = y1.x + inv * acc[4]; o[5] = y1.y + inv * acc[5];
        o[6] = y1.z + inv * acc[6]; o[7] = y1.w + inv * acc[7];
        size_t base = (size_t)node * 40 + cg * 8;
        if (outBf16) {
            v8us ov;
            for (int i = 0; i < 8; ++i) ov[i] = f2b(o[i]);
            *(v8us*)((ushort_t*)out + base) = ov;
        } else {
            float4* op = (float4*)((float*)out + base);
            op[0] = (float4){o[0], o[1], o[2], o[3]};
            op[1] = (float4){o[4], o[5], o[6], o[7]};
        }
    }
}

__global__ void k_zero16(ushort_t* p, int n) {
    int i = blockIdx.x * 256 + threadIdx.x;
    if (i < n) p[i] = 0;
}

// ---------------- launch ----------------

extern "C" void kernel_launch(void* const* d_in, const int* in_sizes, int n_in,
                              void* d_out, int out_size, void* d_ws, size_t ws_size,
                              hipStream_t stream) {
    const int* src = (const int*)d_in[1];
    const int* dst = (const int*)d_in[2];

    const int N = N_NODES, E = N_EDGES;

    char* ws = (char*)d_ws;
    size_t o = 0;
    auto alloc = [&](size_t bytes) {
        char* p = ws + o;
        o = (o + bytes + 511) & ~(size_t)511;
        return p;
    };
    int* flag      = (int*)alloc(4);
    float* inv_deg = (float*)alloc(N * 4);
    int* rs        = (int*)alloc((N + 1) * 4);
    int* bcnt      = (int*)alloc(NBUCK * 4);
    int* boff      = (int*)alloc(NBUCK * 4);
    int* bcur      = (int*)alloc(NBUCK * 4);
    int* es        = (int*)alloc((size_t)E * 4);
    ushort_t* xbuf = (ushort_t*)alloc((size_t)N * 128 * 2);
    char* aux_raw  = (char*)alloc((size_t)N * 128 * 2);   // 25.6 MB multi-use window
    uint* packed   = (uint*)aux_raw;                       // pre-CSR only
    ushort_t* h3   = (ushort_t*)aux_raw;                   // layer 3 only (8 MB)
    float* y3      = (float*)(aux_raw + (size_t)N * 40 * 2 + 512);  // 16 MB after h3
    ushort_t* conv0 = (ushort_t*)alloc((size_t)N * 128 * 2);
    ushort_t* Wt[6];
    Wt[0] = (ushort_t*)alloc(128 * 128 * 2);
    Wt[1] = (ushort_t*)alloc(128 * 128 * 2);
    Wt[2] = (ushort_t*)alloc(128 * 128 * 2);
    Wt[3] = (ushort_t*)alloc(128 * 128 * 2);
    Wt[4] = (ushort_t*)alloc(48 * 128 * 2);
    Wt[5] = (ushort_t*)alloc(48 * 128 * 2);
    size_t need = o;

    if (ws_size < need) {
        k_zero16<<<(out_size + 255) / 256, 256, 0, stream>>>((ushort_t*)d_out, out_size);
        return;
    }

    int nb_gemm = (N + 127) / 128;   // 782
    int nb_agg = (N + 3) / 4;        // 25000

    // dtype detect; weight transpose-convert (+bcnt zero); feat convert + bucket hist
    k_sniff<<<1, 256, 0, stream>>>((const uint*)d_in[0], flag);
    WConvArgs wa;
    wa.srcW[0] = d_in[3]; wa.srcW[1] = d_in[4];
    wa.srcW[2] = d_in[6]; wa.srcW[3] = d_in[7];
    wa.srcW[4] = d_in[9]; wa.srcW[5] = d_in[10];
    for (int i = 0; i < 6; ++i) wa.dstW[i] = Wt[i];
    k_conv_weights<<<305, 256, 0, stream>>>(wa, flag, bcnt);
    k_convfeat_bhist<<<NB_CONV + NTILE, 256, 0, stream>>>(d_in[0], conv0, flag, dst, bcnt);

    const float* b1 = (const float*)d_in[5];
    const float* b2 = (const float*)d_in[8];
    const float* b3 = (const float*)d_in[11];

    // CSR via bucket sort
    k_bscan<<<1, 1024, 0, stream>>>(bcnt, boff, bcur);
    k_bscatter<<<NTILE, 256, 0, stream>>>(src, dst, bcur, packed);
    k_binsort<<<NBUCK, 256, 0, stream>>>(packed, bcnt, boff, rs, inv_deg, es);

    // Layer 1 (fused agg+GEMM): gather conv0 -> xbuf
    k_fused<true><<<NBUCK, 512, 0, stream>>>(rs, es, inv_deg, conv0, Wt[0], Wt[1], b1, xbuf, N);
    // Layer 2 (fused): gather xbuf -> conv0 (ping-pong, no in-place race)
    k_fused<true><<<NBUCK, 512, 0, stream>>>(rs, es, inv_deg, xbuf, Wt[2], Wt[3], b2, conv0, N);
    // Layer 3: split GEMM on conv0, then 40-col aggregation
    k_gemm_split_g<<<nb_gemm, 256, 0, stream>>>(conv0, Wt[4], Wt[5], b3, y3, h3, N);
    k_agg3<<<nb_agg, 256, 0, stream>>>(rs, es, inv_deg, h3, y3, d_out, flag, N);
}

// Round 9
// 463.388 us; speedup vs baseline: 1.1070x; 1.1070x over previous
//
#include <hip/hip_runtime.h>

typedef short v8s __attribute__((ext_vector_type(8)));
typedef unsigned short v8us __attribute__((ext_vector_type(8)));
typedef float v4f __attribute__((ext_vector_type(4)));
typedef float v2f __attribute__((ext_vector_type(2)));
typedef unsigned int uint;
typedef unsigned short ushort_t;

#define N_NODES 100000
#define N_EDGES 1600000
#define NBUCK 782           // ceil(100000/128); bucket = dst>>7
#define TILE 4096
#define NTILE 391           // ceil(1600000/4096)
#define NB_CONV 12500       // 3.2M 4-elem feature groups / 256
#define NB_W 304            // weight conv/transpose blocks
#define AXLD 136            // LDS x2 row stride (shorts): 272 B = 17 x 16 B

__device__ __forceinline__ unsigned short f2b(float f) {
    uint u = __float_as_uint(f);
    uint r = u + 0x7FFFu + ((u >> 16) & 1u);   // RNE
    return (unsigned short)(r >> 16);
}
// accumulate 2 bf16 (packed in one dword) into a float2 accumulator (v_pk_add_f32 path)
__device__ __forceinline__ void acc2_bf16(v2f& acc, uint d) {
    v2f t;
    t.x = __uint_as_float(d << 16);
    t.y = __uint_as_float(d & 0xFFFF0000u);
    acc += t;
}

// ---------------- prep: weight transpose-convert + feature convert + bucket hist ----------------
// Inputs are f32 (proven: R2 NaN / R3 pass disambiguation).
struct WConvArgs {
    const float* srcW[6];
    ushort_t* dstW[6];
};
__global__ __launch_bounds__(256) void k_prep(WConvArgs a,
                                              const float4* __restrict__ featIn,
                                              ushort_t* __restrict__ featOut,
                                              const int* __restrict__ dst,
                                              int* __restrict__ bcnt) {
    __shared__ int h[NBUCK];
    int b = blockIdx.x, tid = threadIdx.x;
    if (b < NB_W) {
        // weights: Wt[n][k] from W[k][n]; H=40 tensors padded to 48 rows
        int j, lb, H;
        if (b < 256)      { j = b >> 6; lb = b & 63; H = 128; }
        else if (b < 276) { j = 4; lb = b - 256; H = 40; }
        else if (b < 280) {
            int idx = (b - 276) * 256 + tid;
            a.dstW[4][(40 + idx / 128) * 128 + (idx & 127)] = 0; return;
        }
        else if (b < 300) { j = 5; lb = b - 280; H = 40; }
        else {
            int idx = (b - 300) * 256 + tid;
            a.dstW[5][(40 + idx / 128) * 128 + (idx & 127)] = 0; return;
        }
        int idx = lb * 256 + tid;
        if (idx >= 128 * H) return;
        int k = idx / H, n = idx % H;
        a.dstW[j][n * 128 + k] = f2b(a.srcW[j][idx]);
        return;
    }
    if (b < NB_W + NB_CONV) {
        int i = (b - NB_W) * 256 + tid;
        float4 v = featIn[i];
        ushort4 o;
        o.x = f2b(v.x); o.y = f2b(v.y); o.z = f2b(v.z); o.w = f2b(v.w);
        ((ushort4*)featOut)[i] = o;
        return;
    }
    int t = b - NB_W - NB_CONV;
    for (int i = tid; i < NBUCK; i += 256) h[i] = 0;
    __syncthreads();
    int t0 = t * TILE;
    int t1 = t0 + TILE; if (t1 > N_EDGES) t1 = N_EDGES;
    for (int i = t0 + tid; i < t1; i += 256) atomicAdd(&h[dst[i] >> 7], 1);
    __syncthreads();
    for (int i = tid; i < NBUCK; i += 256)
        if (h[i]) atomicAdd(&bcnt[i], h[i]);
}

// ---------------- bucket scan ----------------
__global__ __launch_bounds__(1024) void k_bscan(const int* __restrict__ bcnt,
                                                int* __restrict__ boff,
                                                int* __restrict__ bcur) {
    __shared__ int sd[1024];
    int tid = threadIdx.x;
    int v = (tid < NBUCK) ? bcnt[tid] : 0;
    sd[tid] = v; __syncthreads();
    int val = v;
    for (int off = 1; off < 1024; off <<= 1) {
        int t = (tid >= off) ? sd[tid - off] : 0;
        __syncthreads();
        val += t; sd[tid] = val;
        __syncthreads();
    }
    if (tid < NBUCK) {
        int excl = val - v;
        boff[tid] = excl;
        bcur[tid] = excl;
    }
}

// ---------------- tile-local binning -> packed (dstLocal7 | src17) ----------------
__global__ __launch_bounds__(256) void k_bscatter(const int* __restrict__ src,
                                                  const int* __restrict__ dst,
                                                  int* __restrict__ bcur,
                                                  uint* __restrict__ packed) {
    __shared__ int h[NBUCK];
    __shared__ int base[NBUCK];
    int tid = threadIdx.x;
    for (int i = tid; i < NBUCK; i += 256) h[i] = 0;
    __syncthreads();
    int t0 = blockIdx.x * TILE;
    int t1 = t0 + TILE; if (t1 > N_EDGES) t1 = N_EDGES;
    for (int i = t0 + tid; i < t1; i += 256) atomicAdd(&h[dst[i] >> 7], 1);
    __syncthreads();
    for (int i = tid; i < NBUCK; i += 256) {
        int c = h[i];
        base[i] = c ? atomicAdd(&bcur[i], c) : 0;
        h[i] = 0;
    }
    __syncthreads();
    for (int i = t0 + tid; i < t1; i += 256) {
        int d = dst[i];
        int b = d >> 7;
        int r = atomicAdd(&h[b], 1);
        packed[base[b] + r] = ((uint)(d & 127) << 17) | (uint)src[i];
    }
}

// ---------------- one block per bucket: counting sort -> es, rs, inv_deg ----------------
__global__ __launch_bounds__(256) void k_binsort(const uint* __restrict__ packed,
                                                 const int* __restrict__ bcnt,
                                                 const int* __restrict__ boff,
                                                 int* __restrict__ rs,
                                                 float* __restrict__ inv_deg,
                                                 int* __restrict__ es) {
    __shared__ int hist[128], start[128], cur[128];
    int tid = threadIdx.x;
    int b = blockIdx.x;
    int nb = bcnt[b], off = boff[b];
    if (tid < 128) hist[tid] = 0;
    __syncthreads();
    for (int i = tid; i < nb; i += 256) atomicAdd(&hist[packed[off + i] >> 17], 1);
    __syncthreads();
    if (tid < 128) start[tid] = hist[tid];
    __syncthreads();
    for (int o = 1; o < 128; o <<= 1) {
        int v = (tid < 128 && tid >= o) ? start[tid - o] : 0;
        __syncthreads();
        if (tid < 128) start[tid] += v;
        __syncthreads();
    }
    if (tid < 128) {
        int excl = start[tid] - hist[tid];
        int node = b * 128 + tid;
        if (node < N_NODES) {
            rs[node] = off + excl;
            int d = hist[tid];
            inv_deg[node] = 1.0f / (float)(d > 1 ? d : 1);
        }
        cur[tid] = excl;
    }
    if (b == NBUCK - 1 && tid == 0) rs[N_NODES] = N_EDGES;
    __syncthreads();
    for (int i = tid; i < nb; i += 256) {
        uint p = packed[off + i];
        int k = p >> 17;
        int pos = atomicAdd(&cur[k], 1);
        es[off + pos] = (int)(p & 0x1FFFFu);
    }
}

// ---------------- Aggregation (H=128): wave/node, 4 slots x 16 cols, unroll x4 ----------
__global__ __launch_bounds__(256) void k_agg(
    const int* __restrict__ rs,
    const int* __restrict__ es,
    const float* __restrict__ inv_deg,
    const ushort_t* __restrict__ x,
    ushort_t* __restrict__ ax,
    int n) {
    int tid = threadIdx.x;
    int wave = tid >> 6, lane = tid & 63;
    int node = blockIdx.x * 4 + wave;
    if (node >= n) return;
    int sub = lane >> 4;
    int cg = lane & 15;

    int s0 = rs[node], s1 = rs[node + 1];
    v2f acc2[4];
    for (int i = 0; i < 4; ++i) acc2[i] = (v2f){0.f, 0.f};

    int e = s0 + sub;
    for (; e + 12 < s1; e += 16) {
        int sA = es[e], sB = es[e + 4], sC = es[e + 8], sD = es[e + 12];
        uint4 dA = *(const uint4*)(x + (size_t)sA * 128 + cg * 8);
        uint4 dB = *(const uint4*)(x + (size_t)sB * 128 + cg * 8);
        uint4 dC = *(const uint4*)(x + (size_t)sC * 128 + cg * 8);
        uint4 dD = *(const uint4*)(x + (size_t)sD * 128 + cg * 8);
        acc2_bf16(acc2[0], dA.x); acc2_bf16(acc2[1], dA.y); acc2_bf16(acc2[2], dA.z); acc2_bf16(acc2[3], dA.w);
        acc2_bf16(acc2[0], dB.x); acc2_bf16(acc2[1], dB.y); acc2_bf16(acc2[2], dB.z); acc2_bf16(acc2[3], dB.w);
        acc2_bf16(acc2[0], dC.x); acc2_bf16(acc2[1], dC.y); acc2_bf16(acc2[2], dC.z); acc2_bf16(acc2[3], dC.w);
        acc2_bf16(acc2[0], dD.x); acc2_bf16(acc2[1], dD.y); acc2_bf16(acc2[2], dD.z); acc2_bf16(acc2[3], dD.w);
    }
    for (; e < s1; e += 4) {
        int sA = es[e];
        uint4 dA = *(const uint4*)(x + (size_t)sA * 128 + cg * 8);
        acc2_bf16(acc2[0], dA.x); acc2_bf16(acc2[1], dA.y); acc2_bf16(acc2[2], dA.z); acc2_bf16(acc2[3], dA.w);
    }
    float acc[8];
    for (int i = 0; i < 4; ++i) { acc[2 * i] = acc2[i].x; acc[2 * i + 1] = acc2[i].y; }
    for (int off = 16; off < 64; off <<= 1)
        for (int i = 0; i < 8; ++i) acc[i] += __shfl_xor(acc[i], off);

    if (sub == 0) {
        float inv = inv_deg[node];
        v8us ov;
        for (int i = 0; i < 8; ++i) ov[i] = f2b(inv * acc[i]);
        *(v8us*)(ax + (size_t)node * 128 + cg * 8) = ov;
    }
}

// ---------------- Barrier-free dual-A GEMM (layer 1): out = relu(x@Ws + ax@Wn + b) ----------
__global__ __launch_bounds__(256) void k_gemm2_g(
    const ushort_t* __restrict__ x,
    const ushort_t* __restrict__ ax,
    const ushort_t* __restrict__ Wts,
    const ushort_t* __restrict__ Wtn,
    const float* __restrict__ bias,
    ushort_t* out,
    int n) {
    int tid = threadIdx.x;
    int wave = tid >> 6, lane = tid & 63;
    int quad = lane >> 4, l16 = lane & 15;
    int rowBase = blockIdx.x * 128 + wave * 32;

    v4f accS[2][8], accN[2][8];
    for (int rt = 0; rt < 2; ++rt)
        for (int t = 0; t < 8; ++t) {
            accS[rt][t] = (v4f){0.f, 0.f, 0.f, 0.f};
            accN[rt][t] = (v4f){0.f, 0.f, 0.f, 0.f};
        }

    for (int kk = 0; kk < 4; ++kk) {
        v8s a1[2], a2[2];
        for (int rt = 0; rt < 2; ++rt) {
            int row = rowBase + rt * 16 + l16;
            if (row >= n) row = n - 1;
            size_t off = (size_t)row * 128 + kk * 32 + quad * 8;
            a1[rt] = *(const v8s*)(x + off);
            a2[rt] = *(const v8s*)(ax + off);
        }
        for (int t = 0; t < 8; ++t) {
            size_t bo = (size_t)(t * 16 + l16) * 128 + kk * 32 + quad * 8;
            const v8s bs = *(const v8s*)(Wts + bo);
            const v8s bn = *(const v8s*)(Wtn + bo);
            for (int rt = 0; rt < 2; ++rt) {
                accS[rt][t] = __builtin_amdgcn_mfma_f32_16x16x32_bf16(a1[rt], bs, accS[rt][t], 0, 0, 0);
                accN[rt][t] = __builtin_amdgcn_mfma_f32_16x16x32_bf16(a2[rt], bn, accN[rt][t], 0, 0, 0);
            }
        }
    }

    for (int rt = 0; rt < 2; ++rt)
        for (int t = 0; t < 8; ++t) {
            int col = t * 16 + l16;
            float bv = bias[col];
            for (int r = 0; r < 4; ++r) {
                int row = rowBase + rt * 16 + quad * 4 + r;
                if (row < n) {
                    float v = accS[rt][t][r] + accN[rt][t][r] + bv;
                    v = fmaxf(v, 0.f);
                    out[(size_t)row * 128 + col] = f2b(v);
                }
            }
        }
}

// ---------------- Layer-2 GEMM fused with layer-3 split GEMM ----------------
// Phase 1: x2 = relu(x@Ws2 + ax@Wn2 + b2) -> LDS (never written to global).
// Phase 2: y3 = x2@Ws3 + b3 (f32), h3 = x2@Wn3 (bf16), Wt3 padded to 48 rows.
__global__ __launch_bounds__(256) void k_gemm2s(
    const ushort_t* __restrict__ x,
    const ushort_t* __restrict__ ax,
    const ushort_t* __restrict__ Wts2,
    const ushort_t* __restrict__ Wtn2,
    const float* __restrict__ b2,
    const ushort_t* __restrict__ Wts3,
    const ushort_t* __restrict__ Wtn3,
    const float* __restrict__ b3,
    float* __restrict__ y3,
    ushort_t* __restrict__ h3,
    int n) {
    __shared__ ushort_t x2s[128 * AXLD];   // 34.8 KB
    int tid = threadIdx.x;
    int wave = tid >> 6, lane = tid & 63;
    int quad = lane >> 4, l16 = lane & 15;
    int b = blockIdx.x;

    // ---- Phase 1: layer-2 dual GEMM -> LDS ----
    {
        int rowBase = b * 128 + wave * 32;
        v4f accS[2][8], accN[2][8];
        for (int rt = 0; rt < 2; ++rt)
            for (int t = 0; t < 8; ++t) {
                accS[rt][t] = (v4f){0.f, 0.f, 0.f, 0.f};
                accN[rt][t] = (v4f){0.f, 0.f, 0.f, 0.f};
            }
        for (int kk = 0; kk < 4; ++kk) {
            v8s a1[2], a2[2];
            for (int rt = 0; rt < 2; ++rt) {
                int row = rowBase + rt * 16 + l16;
                if (row >= n) row = n - 1;
                size_t off = (size_t)row * 128 + kk * 32 + quad * 8;
                a1[rt] = *(const v8s*)(x + off);
                a2[rt] = *(const v8s*)(ax + off);
            }
            for (int t = 0; t < 8; ++t) {
                size_t bo = (size_t)(t * 16 + l16) * 128 + kk * 32 + quad * 8;
                const v8s bs = *(const v8s*)(Wts2 + bo);
                const v8s bn = *(const v8s*)(Wtn2 + bo);
                for (int rt = 0; rt < 2; ++rt) {
                    accS[rt][t] = __builtin_amdgcn_mfma_f32_16x16x32_bf16(a1[rt], bs, accS[rt][t], 0, 0, 0);
                    accN[rt][t] = __builtin_amdgcn_mfma_f32_16x16x32_bf16(a2[rt], bn, accN[rt][t], 0, 0, 0);
                }
            }
        }
        for (int rt = 0; rt < 2; ++rt)
            for (int t = 0; t < 8; ++t) {
                int col = t * 16 + l16;
                float bv = b2[col];
                for (int r = 0; r < 4; ++r) {
                    int rowL = wave * 32 + rt * 16 + quad * 4 + r;
                    float v = accS[rt][t][r] + accN[rt][t][r] + bv;
                    v = fmaxf(v, 0.f);
                    x2s[rowL * AXLD + col] = f2b(v);
                }
            }
    }
    __syncthreads();

    // ---- Phase 2: layer-3 split GEMM from LDS ----
    {
        constexpr int H = 40;
        int rowBaseL = wave * 32;
        v4f accS[2][3], accN[2][3];
        for (int rt = 0; rt < 2; ++rt)
            for (int t = 0; t < 3; ++t) {
                accS[rt][t] = (v4f){0.f, 0.f, 0.f, 0.f};
                accN[rt][t] = (v4f){0.f, 0.f, 0.f, 0.f};
            }
        for (int kk = 0; kk < 4; ++kk) {
            v8s a1[2];
            for (int rt = 0; rt < 2; ++rt)
                a1[rt] = *(const v8s*)(&x2s[(rowBaseL + rt * 16 + l16) * AXLD + kk * 32 + quad * 8]);
            for (int t = 0; t < 3; ++t) {
                size_t bo = (size_t)(t * 16 + l16) * 128 + kk * 32 + quad * 8;
                const v8s bs = *(const v8s*)(Wts3 + bo);
                const v8s bn = *(const v8s*)(Wtn3 + bo);
                for (int rt = 0; rt < 2; ++rt) {
                    accS[rt][t] = __builtin_amdgcn_mfma_f32_16x16x32_bf16(a1[rt], bs, accS[rt][t], 0, 0, 0);
                    accN[rt][t] = __builtin_amdgcn_mfma_f32_16x16x32_bf16(a1[rt], bn, accN[rt][t], 0, 0, 0);
                }
            }
        }
        for (int rt = 0; rt < 2; ++rt)
            for (int t = 0; t < 3; ++t) {
                int col = t * 16 + l16;
                if (col < H) {
                    float bv = b3[col];
                    for (int r = 0; r < 4; ++r) {
                        int row = b * 128 + rowBaseL + rt * 16 + quad * 4 + r;
                        if (row < n) {
                            size_t o = (size_t)row * H + col;
                            y3[o] = accS[rt][t][r] + bv;
                            h3[o] = f2b(accN[rt][t][r]);
                        }
                    }
                }
            }
    }
}

// ---------------- Layer-3 aggregation (H=40): 8 slots x 8 cols (5 active), f32 out ----------
__global__ __launch_bounds__(256) void k_agg3(
    const int* __restrict__ rs,
    const int* __restrict__ es,
    const float* __restrict__ inv_deg,
    const ushort_t* __restrict__ h3,
    const float* __restrict__ y3,
    float* __restrict__ out,
    int n) {
    int tid = threadIdx.x;
    int wave = tid >> 6, lane = tid & 63;
    int node = blockIdx.x * 4 + wave;
    if (node >= n) return;
    int sub = lane >> 3;        // 8 edge slots
    int cg = lane & 7;          // col group of 8 (0..4 active)
    bool act = (cg < 5);

    int s0 = rs[node], s1 = rs[node + 1];
    v2f acc2[4];
    for (int i = 0; i < 4; ++i) acc2[i] = (v2f){0.f, 0.f};

    if (act) {
        int e = s0 + sub;
        for (; e + 8 < s1; e += 16) {
            int sA = es[e], sB = es[e + 8];
            uint4 dA = *(const uint4*)(h3 + (size_t)sA * 40 + cg * 8);
            uint4 dB = *(const uint4*)(h3 + (size_t)sB * 40 + cg * 8);
            acc2_bf16(acc2[0], dA.x); acc2_bf16(acc2[1], dA.y); acc2_bf16(acc2[2], dA.z); acc2_bf16(acc2[3], dA.w);
            acc2_bf16(acc2[0], dB.x); acc2_bf16(acc2[1], dB.y); acc2_bf16(acc2[2], dB.z); acc2_bf16(acc2[3], dB.w);
        }
        if (e < s1) {
            int sA = es[e];
            uint4 dA = *(const uint4*)(h3 + (size_t)sA * 40 + cg * 8);
            acc2_bf16(acc2[0], dA.x); acc2_bf16(acc2[1], dA.y); acc2_bf16(acc2[2], dA.z); acc2_bf16(acc2[3], dA.w);
        }
    }
    float acc[8];
    for (int i = 0; i < 4; ++i) { acc[2 * i] = acc2[i].x; acc[2 * i + 1] = acc2[i].y; }
    for (int off = 8; off < 64; off <<= 1)
        for (int i = 0; i < 8; ++i) acc[i] += __shfl_xor(acc[i], off);

    if (sub == 0 && act) {
        float inv = inv_deg[node];
        const float4* yp = (const float4*)(y3 + (size_t)node * 40 + cg * 8);
        float4 y0 = yp[0], y1 = yp[1];
        size_t base = (size_t)node * 40 + cg * 8;
        float4* op = (float4*)(out + base);
        op[0] = (float4){y0.x + inv * acc[0], y0.y + inv * acc[1],
                         y0.z + inv * acc[2], y0.w + inv * acc[3]};
        op[1] = (float4){y1.x + inv * acc[4], y1.y + inv * acc[5],
                         y1.z + inv * acc[6], y1.w + inv * acc[7]};
    }
}

__global__ void k_zero16(ushort_t* p, int n) {
    int i = blockIdx.x * 256 + threadIdx.x;
    if (i < n) p[i] = 0;
}

// ---------------- launch ----------------

extern "C" void kernel_launch(void* const* d_in, const int* in_sizes, int n_in,
                              void* d_out, int out_size, void* d_ws, size_t ws_size,
                              hipStream_t stream) {
    const int* src = (const int*)d_in[1];
    const int* dst = (const int*)d_in[2];

    const int N = N_NODES, E = N_EDGES;

    char* ws = (char*)d_ws;
    size_t o = 0;
    auto alloc = [&](size_t bytes) {
        char* p = ws + o;
        o = (o + bytes + 511) & ~(size_t)511;
        return p;
    };
    float* inv_deg = (float*)alloc(N * 4);
    int* rs        = (int*)alloc((N + 1) * 4);
    int* bcnt      = (int*)alloc(NBUCK * 4);
    int* boff      = (int*)alloc(NBUCK * 4);
    int* bcur      = (int*)alloc(NBUCK * 4);
    int* es        = (int*)alloc((size_t)E * 4);
    ushort_t* xbuf = (ushort_t*)alloc((size_t)N * 128 * 2);
    char* aggX_raw = (char*)alloc((size_t)N * 128 * 2);   // 25.6 MB: packed, then aggX
    ushort_t* aggX = (ushort_t*)aggX_raw;
    uint* packed   = (uint*)aggX_raw;                      // pre-CSR only
    char* conv_raw = (char*)alloc((size_t)N * 128 * 2);   // 25.6 MB: conv0, then h3+y3
    ushort_t* conv0 = (ushort_t*)conv_raw;
    ushort_t* h3   = (ushort_t*)conv_raw;                  // 8 MB (layer 3)
    float* y3      = (float*)(conv_raw + (size_t)N * 40 * 2 + 512);  // 16 MB after h3
    ushort_t* Wt[6];
    Wt[0] = (ushort_t*)alloc(128 * 128 * 2);
    Wt[1] = (ushort_t*)alloc(128 * 128 * 2);
    Wt[2] = (ushort_t*)alloc(128 * 128 * 2);
    Wt[3] = (ushort_t*)alloc(128 * 128 * 2);
    Wt[4] = (ushort_t*)alloc(48 * 128 * 2);
    Wt[5] = (ushort_t*)alloc(48 * 128 * 2);
    size_t need = o;

    if (ws_size < need) {
        k_zero16<<<(out_size + 255) / 256, 256, 0, stream>>>((ushort_t*)d_out, out_size);
        return;
    }

    int nb_agg = (N + 3) / 4;        // 25000

    const float* b1 = (const float*)d_in[5];
    const float* b2 = (const float*)d_in[8];
    const float* b3 = (const float*)d_in[11];

    // prep: zero bcnt (async memset is graph-capturable), then weights+feat+hist in one kernel
    hipMemsetAsync(bcnt, 0, NBUCK * 4, stream);
    WConvArgs wa;
    wa.srcW[0] = (const float*)d_in[3]; wa.srcW[1] = (const float*)d_in[4];
    wa.srcW[2] = (const float*)d_in[6]; wa.srcW[3] = (const float*)d_in[7];
    wa.srcW[4] = (const float*)d_in[9]; wa.srcW[5] = (const float*)d_in[10];
    for (int i = 0; i < 6; ++i) wa.dstW[i] = Wt[i];
    k_prep<<<NB_W + NB_CONV + NTILE, 256, 0, stream>>>(wa, (const float4*)d_in[0], conv0, dst, bcnt);

    // CSR via bucket sort
    k_bscan<<<1, 1024, 0, stream>>>(bcnt, boff, bcur);
    k_bscatter<<<NTILE, 256, 0, stream>>>(src, dst, bcur, packed);
    k_binsort<<<NBUCK, 256, 0, stream>>>(packed, bcnt, boff, rs, inv_deg, es);

    // Layer 1: aggregate conv0 -> aggX; GEMM -> xbuf
    k_agg<<<nb_agg, 256, 0, stream>>>(rs, es, inv_deg, conv0, aggX, N);
    k_gemm2_g<<<NBUCK, 256, 0, stream>>>(conv0, aggX, Wt[0], Wt[1], b1, xbuf, N);
    // Layer 2: aggregate xbuf -> aggX; fused layer-2 GEMM + layer-3 split GEMM -> y3,h3
    k_agg<<<nb_agg, 256, 0, stream>>>(rs, es, inv_deg, xbuf, aggX, N);
    k_gemm2s<<<NBUCK, 256, 0, stream>>>(xbuf, aggX, Wt[2], Wt[3], b2, Wt[4], Wt[5], b3, y3, h3, N);
    // Layer 3 aggregation -> d_out (f32)
    k_agg3<<<nb_agg, 256, 0, stream>>>(rs, es, inv_deg, h3, y3, (float*)d_out, N);
}